// Round 2
// baseline (289.475 us; speedup 1.0000x reference)
//
#include <hip/hip_runtime.h>

#define NB 8
#define NN 2048
#define DIN 256
#define HID 64
#define JSPLIT 8

typedef __bf16 bf16x8_t __attribute__((ext_vector_type(8)));
typedef float f32x16_t __attribute__((ext_vector_type(16)));

// ---------------------------------------------------------------------------
// k1: Wh = x@W (fp32), f1 = Wh@a1, f2 = Wh@a2, and write WhT hi/lo bf16 split
// transposed to [b][h][n] so k3's B-fragments are contiguous 16B global loads.
// ---------------------------------------------------------------------------
__global__ __launch_bounds__(256) void k_wh(
    const float* __restrict__ x, const float* __restrict__ W,
    const float* __restrict__ a,
    __bf16* __restrict__ wht_hi, __bf16* __restrict__ wht_lo,
    float* __restrict__ f1, float* __restrict__ f2)
{
    __shared__ float smem[DIN * 64];   // 64 KB, reused later as T[h][row]
    const int t = threadIdx.x;
    const int g0 = blockIdx.x * 64;    // global row base (over B*N)
    const int b = g0 >> 11;
    const int n0 = g0 & (NN - 1);

    const float4* x4 = (const float4*)x;
#pragma unroll
    for (int it = 0; it < 16; ++it) {
        int c = t + it * 256;
        int row = c & 63;
        int dg = c >> 6;
        float4 v = x4[(size_t)(g0 + row) * 64 + dg];
        smem[(dg * 4 + 0) * 64 + row] = v.x;
        smem[(dg * 4 + 1) * 64 + row] = v.y;
        smem[(dg * 4 + 2) * 64 + row] = v.z;
        smem[(dg * 4 + 3) * 64 + row] = v.w;
    }
    __syncthreads();

    const int hq = t & 15;   // h-quad: cols hq*4..+3
    const int rg = t >> 4;   // row-group: rows rg*4..+3
    const float4* W4 = (const float4*)W;
    float acc[4][4] = {};
#pragma unroll 8
    for (int d = 0; d < DIN; ++d) {
        float4 wv = W4[d * 16 + hq];
        float4 xv = *(const float4*)&smem[d * 64 + rg * 4];
        float xr[4] = {xv.x, xv.y, xv.z, xv.w};
        float wk[4] = {wv.x, wv.y, wv.z, wv.w};
#pragma unroll
        for (int r = 0; r < 4; ++r)
#pragma unroll
            for (int k = 0; k < 4; ++k) acc[r][k] += xr[r] * wk[k];
    }

    // f1/f2: reduce over h (16 hq-lanes per row-group; xor<16 stays in group)
    float4 a1v = ((const float4*)a)[hq];
    float4 a2v = ((const float4*)a)[16 + hq];
#pragma unroll
    for (int r = 0; r < 4; ++r) {
        float p1 = acc[r][0] * a1v.x + acc[r][1] * a1v.y + acc[r][2] * a1v.z + acc[r][3] * a1v.w;
        float p2 = acc[r][0] * a2v.x + acc[r][1] * a2v.y + acc[r][2] * a2v.z + acc[r][3] * a2v.w;
#pragma unroll
        for (int m = 1; m < 16; m <<= 1) {
            p1 += __shfl_xor(p1, m);
            p2 += __shfl_xor(p2, m);
        }
        if (hq == 0) {
            f1[g0 + rg * 4 + r] = p1;
            f2[g0 + rg * 4 + r] = p2;
        }
    }

    __syncthreads();
    // transpose: T[h][row], 4-row groups XOR-swizzled to break bank conflicts
#pragma unroll
    for (int r = 0; r < 4; ++r)
#pragma unroll
        for (int k = 0; k < 4; ++k) {
            int h = hq * 4 + k;
            int row = rg * 4 + r;
            smem[h * 64 + (((row >> 2) ^ (h & 15)) << 2) + (row & 3)] = acc[r][k];
        }
    __syncthreads();

    const int h = t >> 2;    // 0..63
    const int rc = t & 3;    // 16-row chunk
    union { __bf16 bh[16]; uint4 u4[2]; } uh, ul;
#pragma unroll
    for (int q = 0; q < 4; ++q) {
        float4 v = *(const float4*)&smem[h * 64 + (((rc * 4 + q) ^ (h & 15)) << 2)];
        float vv[4] = {v.x, v.y, v.z, v.w};
#pragma unroll
        for (int e = 0; e < 4; ++e) {
            float val = vv[e];
            __bf16 hi = (__bf16)val;
            __bf16 lo = (__bf16)(val - (float)hi);
            uh.bh[q * 4 + e] = hi;
            ul.bh[q * 4 + e] = lo;
        }
    }
    size_t obase = (size_t)(b * HID + h) * NN + n0 + rc * 16;
    *(uint4*)&wht_hi[obase] = uh.u4[0];
    *(uint4*)&wht_hi[obase + 8] = uh.u4[1];
    *(uint4*)&wht_lo[obase] = ul.u4[0];
    *(uint4*)&wht_lo[obase + 8] = ul.u4[1];
}

// ---------------------------------------------------------------------------
// k2: f2max[b] = max_n f2[b][n]  (feeds the softmax shift bound)
// ---------------------------------------------------------------------------
__global__ __launch_bounds__(256) void k_f2max(
    const float* __restrict__ f2, float* __restrict__ f2mx)
{
    __shared__ float red[4];
    const int b = blockIdx.x, t = threadIdx.x;
    float m = -3.4e38f;
    for (int i = t; i < NN; i += 256) m = fmaxf(m, f2[b * NN + i]);
#pragma unroll
    for (int s = 1; s < 64; s <<= 1) m = fmaxf(m, __shfl_xor(m, s));
    if ((t & 63) == 0) red[t >> 6] = m;
    __syncthreads();
    if (t == 0) f2mx[b] = fmaxf(fmaxf(red[0], red[1]), fmaxf(red[2], red[3]));
}

// ---------------------------------------------------------------------------
// k3: fused masked-softmax + P@Wh via 32x32x16 bf16 MFMA (hi/lo split).
// NO LDS, NO barriers: B-fragments are contiguous 16B global loads from the
// [b][h][n] WhT layout (L1/L2-resident); scores are produced directly in
// A-fragment layout by per-lane VALU. Softmax shift = per-row upper bound
// M_i = lrelu(f1_i + max f2) => single pass, no rescale. j split 8-way across
// blocks (1024 blocks = 4/CU = 16 waves/CU) to hide scattered adj latency.
// ---------------------------------------------------------------------------
__global__ __launch_bounds__(256, 4) void k_attn(
    const int* __restrict__ adj, const __bf16* __restrict__ wht_hi,
    const __bf16* __restrict__ wht_lo, const float* __restrict__ f1,
    const float* __restrict__ f2, const float* __restrict__ f2mx,
    float* __restrict__ accp, float* __restrict__ zp)
{
    const int t = threadIdx.x;
    const int w = t >> 6, lane = t & 63;
    const int bx = blockIdx.x;
    const int js = bx & 7;
    const int it = (bx >> 3) & 15;
    const int b = bx >> 7;
    const int I0 = it * 128 + w * 32;
    const int half = lane >> 5;
    const int m32 = lane & 31;
    const int row = I0 + m32;

    const float f1v = f1[b * NN + row];
    float Mi = f1v + f2mx[b];
    Mi = Mi > 0.f ? Mi : 0.2f * Mi;            // lrelu monotone -> valid bound
    const int* adjrow = adj + (size_t)(b * NN + row) * NN;
    const __bf16* bh0p = wht_hi + (size_t)(b * HID + m32) * NN;
    const __bf16* bh1p = wht_hi + (size_t)(b * HID + m32 + 32) * NN;
    const __bf16* bl0p = wht_lo + (size_t)(b * HID + m32) * NN;
    const __bf16* bl1p = wht_lo + (size_t)(b * HID + m32 + 32) * NN;
    const float* f2p = f2 + b * NN;

    f32x16_t acc0, acc1;
#pragma unroll
    for (int i = 0; i < 16; ++i) { acc0[i] = 0.f; acc1[i] = 0.f; }
    float zacc = 0.f;
    const int jb0 = js * 256;

#pragma unroll 4
    for (int s = 0; s < 16; ++s) {
        const int jl = jb0 + s * 16 + half * 8;   // this lane's 8-j group
        int4 aa = *(const int4*)&adjrow[jl];
        int4 ab = *(const int4*)&adjrow[jl + 4];
        float4 fa = *(const float4*)&f2p[jl];
        float4 fb = *(const float4*)&f2p[jl + 4];
        bf16x8_t bh0 = *(const bf16x8_t*)&bh0p[jl];   // B[k=jl+e][n=m32]
        bf16x8_t bl0 = *(const bf16x8_t*)&bl0p[jl];
        bf16x8_t bh1 = *(const bf16x8_t*)&bh1p[jl];   // B[k=jl+e][n=m32+32]
        bf16x8_t bl1 = *(const bf16x8_t*)&bl1p[jl];
        int av[8] = {aa.x, aa.y, aa.z, aa.w, ab.x, ab.y, ab.z, ab.w};
        float fv[8] = {fa.x, fa.y, fa.z, fa.w, fb.x, fb.y, fb.z, fb.w};
        bf16x8_t ahi, alo;
#pragma unroll
        for (int jj = 0; jj < 8; ++jj) {
            float t1 = f1v + fv[jj];
            t1 = t1 > 0.f ? t1 : 0.2f * t1;
            float pv = av[jj] > 0
                     ? __builtin_amdgcn_exp2f((t1 - Mi) * 1.4426950408889634f)
                     : 0.f;
            zacc += pv;
            __bf16 hb = (__bf16)pv;
            ahi[jj] = hb;
            alo[jj] = (__bf16)(pv - (float)hb);
        }
        acc0 = __builtin_amdgcn_mfma_f32_32x32x16_bf16(ahi, bh0, acc0, 0, 0, 0);
        acc0 = __builtin_amdgcn_mfma_f32_32x32x16_bf16(ahi, bl0, acc0, 0, 0, 0);
        acc0 = __builtin_amdgcn_mfma_f32_32x32x16_bf16(alo, bh0, acc0, 0, 0, 0);
        acc1 = __builtin_amdgcn_mfma_f32_32x32x16_bf16(ahi, bh1, acc1, 0, 0, 0);
        acc1 = __builtin_amdgcn_mfma_f32_32x32x16_bf16(ahi, bl1, acc1, 0, 0, 0);
        acc1 = __builtin_amdgcn_mfma_f32_32x32x16_bf16(alo, bh1, acc1, 0, 0, 0);
    }

    float zrow = zacc + __shfl_xor(zacc, 32);
    if (lane < 32) zp[(size_t)(js * NB + b) * NN + row] = zrow;
    float* ap = accp + (size_t)(js * NB + b) * NN * HID;
#pragma unroll
    for (int r = 0; r < 16; ++r) {
        int rr = (r & 3) + 8 * (r >> 2) + 4 * half;   // verified C-layout (m74/m101)
        ap[(size_t)(I0 + rr) * HID + m32] = acc0[r];
        ap[(size_t)(I0 + rr) * HID + m32 + 32] = acc1[r];
    }
}

// ---------------------------------------------------------------------------
// k4: out = (sum_js acc_js) / (sum_js Z_js)
// ---------------------------------------------------------------------------
__global__ __launch_bounds__(256) void k_combine(
    const float* __restrict__ accp, const float* __restrict__ zp,
    float* __restrict__ out)
{
    int gid = blockIdx.x * 256 + threadIdx.x;   // 0..262143 (float4 granules)
    int h4 = gid & 15;
    int rowg = gid >> 4;                        // b*N + n
    float z = 0.f;
    float sx = 0.f, sy = 0.f, sz = 0.f, sw = 0.f;
#pragma unroll
    for (int js = 0; js < JSPLIT; ++js) {
        size_t base = (size_t)js * NB * NN;
        z += zp[base + rowg];
        float4 v = ((const float4*)accp)[(base + rowg) * 16 + h4];
        sx += v.x; sy += v.y; sz += v.z; sw += v.w;
    }
    float zi = 1.f / z;
    float4 o = {sx * zi, sy * zi, sz * zi, sw * zi};
    ((float4*)out)[gid] = o;
}

extern "C" void kernel_launch(void* const* d_in, const int* in_sizes, int n_in,
                              void* d_out, int out_size, void* d_ws, size_t ws_size,
                              hipStream_t stream)
{
    const float* x = (const float*)d_in[0];
    const int* adj = (const int*)d_in[1];
    const float* W = (const float*)d_in[2];
    const float* a = (const float*)d_in[3];
    float* out = (float*)d_out;
    char* ws = (char*)d_ws;

    __bf16* wht_hi = (__bf16*)(ws);                          // 2 MB
    __bf16* wht_lo = (__bf16*)(ws + (2u << 20));             // 2 MB
    float* f1   = (float*)(ws + (4u << 20));                 // 64 KB
    float* f2   = (float*)(ws + (4u << 20) + (64u << 10));   // 64 KB
    float* f2mx = (float*)(ws + (4u << 20) + (128u << 10));  // 32 B
    float* accp = (float*)(ws + (5u << 20));                 // 32 MB (8 splits)
    float* zp   = (float*)(ws + (37u << 20));                // 512 KB

    hipLaunchKernelGGL(k_wh, dim3(256), dim3(256), 0, stream, x, W, a, wht_hi, wht_lo, f1, f2);
    hipLaunchKernelGGL(k_f2max, dim3(NB), dim3(256), 0, stream, f2, f2mx);
    hipLaunchKernelGGL(k_attn, dim3(1024), dim3(256), 0, stream, adj, wht_hi, wht_lo, f1, f2, f2mx, accp, zp);
    hipLaunchKernelGGL(k_combine, dim3(1024), dim3(256), 0, stream, accp, zp, out);
}

// Round 3
// 265.753 us; speedup vs baseline: 1.0893x; 1.0893x over previous
//
#include <hip/hip_runtime.h>

#define NB 8
#define NN 2048
#define DIN 256
#define HID 64
#define JSPLIT 4

typedef __bf16 bf16x8_t __attribute__((ext_vector_type(8)));
typedef float f32x16_t __attribute__((ext_vector_type(16)));

// ---------------------------------------------------------------------------
// k1: Wh = x@W (fp32), f1 = Wh@a1, f2 = Wh@a2, and write WhT hi/lo bf16 split
// transposed to [b][h][n] so k3's LDS stage-in is coalesced.
// ---------------------------------------------------------------------------
__global__ __launch_bounds__(256) void k_wh(
    const float* __restrict__ x, const float* __restrict__ W,
    const float* __restrict__ a,
    __bf16* __restrict__ wht_hi, __bf16* __restrict__ wht_lo,
    float* __restrict__ f1, float* __restrict__ f2)
{
    __shared__ float smem[DIN * 64];   // 64 KB, reused later as T[h][row]
    const int t = threadIdx.x;
    const int g0 = blockIdx.x * 64;    // global row base (over B*N)
    const int b = g0 >> 11;
    const int n0 = g0 & (NN - 1);

    const float4* x4 = (const float4*)x;
#pragma unroll
    for (int it = 0; it < 16; ++it) {
        int c = t + it * 256;
        int row = c & 63;
        int dg = c >> 6;
        float4 v = x4[(size_t)(g0 + row) * 64 + dg];
        smem[(dg * 4 + 0) * 64 + row] = v.x;
        smem[(dg * 4 + 1) * 64 + row] = v.y;
        smem[(dg * 4 + 2) * 64 + row] = v.z;
        smem[(dg * 4 + 3) * 64 + row] = v.w;
    }
    __syncthreads();

    const int hq = t & 15;   // h-quad: cols hq*4..+3
    const int rg = t >> 4;   // row-group: rows rg*4..+3
    const float4* W4 = (const float4*)W;
    float acc[4][4] = {};
#pragma unroll 8
    for (int d = 0; d < DIN; ++d) {
        float4 wv = W4[d * 16 + hq];
        float4 xv = *(const float4*)&smem[d * 64 + rg * 4];
        float xr[4] = {xv.x, xv.y, xv.z, xv.w};
        float wk[4] = {wv.x, wv.y, wv.z, wv.w};
#pragma unroll
        for (int r = 0; r < 4; ++r)
#pragma unroll
            for (int k = 0; k < 4; ++k) acc[r][k] += xr[r] * wk[k];
    }

    // f1/f2: reduce over h (16 hq-lanes per row-group; xor<16 stays in group)
    float4 a1v = ((const float4*)a)[hq];
    float4 a2v = ((const float4*)a)[16 + hq];
#pragma unroll
    for (int r = 0; r < 4; ++r) {
        float p1 = acc[r][0] * a1v.x + acc[r][1] * a1v.y + acc[r][2] * a1v.z + acc[r][3] * a1v.w;
        float p2 = acc[r][0] * a2v.x + acc[r][1] * a2v.y + acc[r][2] * a2v.z + acc[r][3] * a2v.w;
#pragma unroll
        for (int m = 1; m < 16; m <<= 1) {
            p1 += __shfl_xor(p1, m);
            p2 += __shfl_xor(p2, m);
        }
        if (hq == 0) {
            f1[g0 + rg * 4 + r] = p1;
            f2[g0 + rg * 4 + r] = p2;
        }
    }

    __syncthreads();
    // transpose: T[h][row], 4-row groups XOR-swizzled to break bank conflicts
#pragma unroll
    for (int r = 0; r < 4; ++r)
#pragma unroll
        for (int k = 0; k < 4; ++k) {
            int h = hq * 4 + k;
            int row = rg * 4 + r;
            smem[h * 64 + (((row >> 2) ^ (h & 15)) << 2) + (row & 3)] = acc[r][k];
        }
    __syncthreads();

    const int h = t >> 2;    // 0..63
    const int rc = t & 3;    // 16-row chunk
    union { __bf16 bh[16]; uint4 u4[2]; } uh, ul;
#pragma unroll
    for (int q = 0; q < 4; ++q) {
        float4 v = *(const float4*)&smem[h * 64 + (((rc * 4 + q) ^ (h & 15)) << 2)];
        float vv[4] = {v.x, v.y, v.z, v.w};
#pragma unroll
        for (int e = 0; e < 4; ++e) {
            float val = vv[e];
            __bf16 hi = (__bf16)val;
            __bf16 lo = (__bf16)(val - (float)hi);
            uh.bh[q * 4 + e] = hi;
            ul.bh[q * 4 + e] = lo;
        }
    }
    size_t obase = (size_t)(b * HID + h) * NN + n0 + rc * 16;
    *(uint4*)&wht_hi[obase] = uh.u4[0];
    *(uint4*)&wht_hi[obase + 8] = uh.u4[1];
    *(uint4*)&wht_lo[obase] = ul.u4[0];
    *(uint4*)&wht_lo[obase + 8] = ul.u4[1];
}

// ---------------------------------------------------------------------------
// k2: f2max[b] = max_n f2[b][n]  (feeds the softmax shift bound)
// ---------------------------------------------------------------------------
__global__ __launch_bounds__(256) void k_f2max(
    const float* __restrict__ f2, float* __restrict__ f2mx)
{
    __shared__ float red[4];
    const int b = blockIdx.x, t = threadIdx.x;
    float m = -3.4e38f;
    for (int i = t; i < NN; i += 256) m = fmaxf(m, f2[b * NN + i]);
#pragma unroll
    for (int s = 1; s < 64; s <<= 1) m = fmaxf(m, __shfl_xor(m, s));
    if ((t & 63) == 0) red[t >> 6] = m;
    __syncthreads();
    if (t == 0) f2mx[b] = fmaxf(fmaxf(red[0], red[1]), fmaxf(red[2], red[3]));
}

// ---------------------------------------------------------------------------
// k3: fused adjacency-pack + masked-softmax + P@Wh (32x32x16 bf16 MFMA hi/lo).
// All global loads coalesced:
//   - adjacency: wave-ballot pack, 256B/instr consecutive-lane loads; each
//     lane keeps its own row's 512 bits in 8 uint64 regs (mask-shift queue
//     keeps all register indices compile-time const).
//   - WhT: LDS staging (round-0 XOR-swizzled layout), coalesced stage-in.
//   - f2: wave-broadcast addresses.
// Zero scattered loads in the hot loop -> TA/L1 serialization gone.
// ---------------------------------------------------------------------------
__global__ __launch_bounds__(256, 2) void k_attn(
    const int* __restrict__ adj, const __bf16* __restrict__ wht_hi,
    const __bf16* __restrict__ wht_lo, const float* __restrict__ f1,
    const float* __restrict__ f2, const float* __restrict__ f2mx,
    float* __restrict__ accp, float* __restrict__ zp)
{
    __shared__ __bf16 whi[64 * 128];   // [h][j-tile], 8-elem groups XOR-swizzled
    __shared__ __bf16 wlo[64 * 128];
    const int t = threadIdx.x;
    const int w = t >> 6, lane = t & 63;
    const int bx = blockIdx.x;
    const int js = bx & 3;
    const int it = (bx >> 2) & 15;
    const int b = bx >> 6;
    const int I0 = it * 128 + w * 32;
    const int half = lane >> 5;
    const int m32 = lane & 31;
    const int row = I0 + m32;
    const int jb0 = js * 512;

    const float f1v = f1[b * NN + row];
    float Mi = f1v + f2mx[b];
    Mi = Mi > 0.f ? Mi : 0.2f * Mi;            // lrelu monotone -> valid bound
    const float LOG2E = 1.4426950408889634f;
    const float negMiL = -Mi * LOG2E;
    const float* f2p = f2 + b * NN;

    // ---- Phase A: ballot-pack this wave's 32 adjacency rows (64 KB, coalesced)
    uint64_t mq[8];
#pragma unroll
    for (int k = 0; k < 8; ++k) mq[k] = 0;
    const int* adjbase = adj + ((size_t)b * NN + I0) * NN + jb0;
#pragma unroll 4
    for (int r = 0; r < 32; ++r) {
        const int* ar = adjbase + (size_t)r * NN;
        bool keep = (m32 == r);
#pragma unroll
        for (int k = 0; k < 8; ++k) {
            unsigned long long bal = __ballot(ar[k * 64 + lane] != 0);
            if (keep) mq[k] = bal;
        }
    }

    f32x16_t acc0, acc1;
#pragma unroll
    for (int i = 0; i < 16; ++i) { acc0[i] = 0.f; acc1[i] = 0.f; }
    float zacc = 0.f;

    for (int stg = 0; stg < 4; ++stg) {
        const int jt = jb0 + stg * 128;
        __syncthreads();
#pragma unroll
        for (int cc = 0; cc < 4; ++cc) {
            int c = t + cc * 256;
            int h = c >> 4, g = c & 15;
            int gp = g ^ (h & 15);
            size_t src = (size_t)(b * HID + h) * NN + jt + g * 8;
            *(uint4*)&whi[h * 128 + gp * 8] = *(const uint4*)&wht_hi[src];
            *(uint4*)&wlo[h * 128 + gp * 8] = *(const uint4*)&wht_lo[src];
        }
        __syncthreads();
#pragma unroll
        for (int s8 = 0; s8 < 8; ++s8) {
            const int jl = jt + s8 * 16 + half * 8;   // this lane's 8-j group
            // mask bits for j in [jl, jl+8): word s8>>2 (const), shift below
            const uint32_t bits8 =
                (uint32_t)(mq[s8 >> 2] >> (((s8 & 3) * 16) + half * 8)) & 0xffu;
            float4 fa = *(const float4*)&f2p[jl];
            float4 fb = *(const float4*)&f2p[jl + 4];
            float fv[8] = {fa.x, fa.y, fa.z, fa.w, fb.x, fb.y, fb.z, fb.w};
            bf16x8_t ahi, alo;
#pragma unroll
            for (int jj = 0; jj < 8; ++jj) {
                float t1 = f1v + fv[jj];
                t1 = fmaxf(t1, 0.2f * t1);
                float pv = (bits8 & (1u << jj))
                         ? __builtin_amdgcn_exp2f(fmaf(t1, LOG2E, negMiL))
                         : 0.f;
                zacc += pv;
                __bf16 hb = (__bf16)pv;
                ahi[jj] = hb;
                alo[jj] = (__bf16)(pv - (float)hb);
            }
            const int gb = 2 * s8 + half;
            const int gx = gb ^ (m32 & 15);
            bf16x8_t bh0 = *(const bf16x8_t*)&whi[m32 * 128 + (gx << 3)];
            bf16x8_t bl0 = *(const bf16x8_t*)&wlo[m32 * 128 + (gx << 3)];
            bf16x8_t bh1 = *(const bf16x8_t*)&whi[(m32 + 32) * 128 + (gx << 3)];
            bf16x8_t bl1 = *(const bf16x8_t*)&wlo[(m32 + 32) * 128 + (gx << 3)];
            acc0 = __builtin_amdgcn_mfma_f32_32x32x16_bf16(ahi, bh0, acc0, 0, 0, 0);
            acc0 = __builtin_amdgcn_mfma_f32_32x32x16_bf16(ahi, bl0, acc0, 0, 0, 0);
            acc0 = __builtin_amdgcn_mfma_f32_32x32x16_bf16(alo, bh0, acc0, 0, 0, 0);
            acc1 = __builtin_amdgcn_mfma_f32_32x32x16_bf16(ahi, bh1, acc1, 0, 0, 0);
            acc1 = __builtin_amdgcn_mfma_f32_32x32x16_bf16(ahi, bl1, acc1, 0, 0, 0);
            acc1 = __builtin_amdgcn_mfma_f32_32x32x16_bf16(alo, bh1, acc1, 0, 0, 0);
        }
        // shift mask queue so next stage uses mq[0], mq[1] (const indices)
#pragma unroll
        for (int k = 0; k < 6; ++k) mq[k] = mq[k + 2];
    }

    float zrow = zacc + __shfl_xor(zacc, 32);
    if (lane < 32) zp[(size_t)(js * NB + b) * NN + row] = zrow;
    float* ap = accp + (size_t)(js * NB + b) * NN * HID;
#pragma unroll
    for (int r = 0; r < 16; ++r) {
        int rr = (r & 3) + 8 * (r >> 2) + 4 * half;   // verified C-layout (m74/m101)
        ap[(size_t)(I0 + rr) * HID + m32] = acc0[r];
        ap[(size_t)(I0 + rr) * HID + m32 + 32] = acc1[r];
    }
}

// ---------------------------------------------------------------------------
// k4: out = (sum_js acc_js) / (sum_js Z_js)
// ---------------------------------------------------------------------------
__global__ __launch_bounds__(256) void k_combine(
    const float* __restrict__ accp, const float* __restrict__ zp,
    float* __restrict__ out)
{
    int gid = blockIdx.x * 256 + threadIdx.x;   // 0..262143 (float4 granules)
    int h4 = gid & 15;
    int rowg = gid >> 4;                        // b*N + n
    float z = 0.f;
    float sx = 0.f, sy = 0.f, sz = 0.f, sw = 0.f;
#pragma unroll
    for (int js = 0; js < JSPLIT; ++js) {
        size_t base = (size_t)js * NB * NN;
        z += zp[base + rowg];
        float4 v = ((const float4*)accp)[(base + rowg) * 16 + h4];
        sx += v.x; sy += v.y; sz += v.z; sw += v.w;
    }
    float zi = 1.f / z;
    float4 o = {sx * zi, sy * zi, sz * zi, sw * zi};
    ((float4*)out)[gid] = o;
}

extern "C" void kernel_launch(void* const* d_in, const int* in_sizes, int n_in,
                              void* d_out, int out_size, void* d_ws, size_t ws_size,
                              hipStream_t stream)
{
    const float* x = (const float*)d_in[0];
    const int* adj = (const int*)d_in[1];
    const float* W = (const float*)d_in[2];
    const float* a = (const float*)d_in[3];
    float* out = (float*)d_out;
    char* ws = (char*)d_ws;

    __bf16* wht_hi = (__bf16*)(ws);                          // 2 MB
    __bf16* wht_lo = (__bf16*)(ws + (2u << 20));             // 2 MB
    float* f1   = (float*)(ws + (4u << 20));                 // 64 KB
    float* f2   = (float*)(ws + (4u << 20) + (64u << 10));   // 64 KB
    float* f2mx = (float*)(ws + (4u << 20) + (128u << 10));  // 32 B
    float* accp = (float*)(ws + (5u << 20));                 // 16 MB (4 splits)
    float* zp   = (float*)(ws + (21u << 20));                // 256 KB

    hipLaunchKernelGGL(k_wh, dim3(256), dim3(256), 0, stream, x, W, a, wht_hi, wht_lo, f1, f2);
    hipLaunchKernelGGL(k_f2max, dim3(NB), dim3(256), 0, stream, f2, f2mx);
    hipLaunchKernelGGL(k_attn, dim3(512), dim3(256), 0, stream, adj, wht_hi, wht_lo, f1, f2, f2mx, accp, zp);
    hipLaunchKernelGGL(k_combine, dim3(1024), dim3(256), 0, stream, accp, zp, out);
}

// Round 4
// 256.304 us; speedup vs baseline: 1.1294x; 1.0369x over previous
//
#include <hip/hip_runtime.h>

#define NB 8
#define NN 2048
#define DIN 256
#define HID 64
#define JSPLIT 8

typedef __bf16 bf16x8_t __attribute__((ext_vector_type(8)));
typedef float f32x16_t __attribute__((ext_vector_type(16)));

// ---------------------------------------------------------------------------
// k1: Wh = x@W (fp32), f1 = Wh@a1, f2 = Wh@a2, and write WhT hi/lo bf16 split
// transposed to [b][h][n] so k3's LDS stage-in is coalesced.
// ---------------------------------------------------------------------------
__global__ __launch_bounds__(256) void k_wh(
    const float* __restrict__ x, const float* __restrict__ W,
    const float* __restrict__ a,
    __bf16* __restrict__ wht_hi, __bf16* __restrict__ wht_lo,
    float* __restrict__ f1, float* __restrict__ f2)
{
    __shared__ float smem[DIN * 64];   // 64 KB, reused later as T[h][row]
    const int t = threadIdx.x;
    const int g0 = blockIdx.x * 64;    // global row base (over B*N)
    const int b = g0 >> 11;
    const int n0 = g0 & (NN - 1);

    const float4* x4 = (const float4*)x;
#pragma unroll
    for (int it = 0; it < 16; ++it) {
        int c = t + it * 256;
        int row = c & 63;
        int dg = c >> 6;
        float4 v = x4[(size_t)(g0 + row) * 64 + dg];
        smem[(dg * 4 + 0) * 64 + row] = v.x;
        smem[(dg * 4 + 1) * 64 + row] = v.y;
        smem[(dg * 4 + 2) * 64 + row] = v.z;
        smem[(dg * 4 + 3) * 64 + row] = v.w;
    }
    __syncthreads();

    const int hq = t & 15;   // h-quad: cols hq*4..+3
    const int rg = t >> 4;   // row-group: rows rg*4..+3
    const float4* W4 = (const float4*)W;
    float acc[4][4] = {};
#pragma unroll 8
    for (int d = 0; d < DIN; ++d) {
        float4 wv = W4[d * 16 + hq];
        float4 xv = *(const float4*)&smem[d * 64 + rg * 4];
        float xr[4] = {xv.x, xv.y, xv.z, xv.w};
        float wk[4] = {wv.x, wv.y, wv.z, wv.w};
#pragma unroll
        for (int r = 0; r < 4; ++r)
#pragma unroll
            for (int k = 0; k < 4; ++k) acc[r][k] += xr[r] * wk[k];
    }

    // f1/f2: reduce over h (16 hq-lanes per row-group; xor<16 stays in group)
    float4 a1v = ((const float4*)a)[hq];
    float4 a2v = ((const float4*)a)[16 + hq];
#pragma unroll
    for (int r = 0; r < 4; ++r) {
        float p1 = acc[r][0] * a1v.x + acc[r][1] * a1v.y + acc[r][2] * a1v.z + acc[r][3] * a1v.w;
        float p2 = acc[r][0] * a2v.x + acc[r][1] * a2v.y + acc[r][2] * a2v.z + acc[r][3] * a2v.w;
#pragma unroll
        for (int m = 1; m < 16; m <<= 1) {
            p1 += __shfl_xor(p1, m);
            p2 += __shfl_xor(p2, m);
        }
        if (hq == 0) {
            f1[g0 + rg * 4 + r] = p1;
            f2[g0 + rg * 4 + r] = p2;
        }
    }

    __syncthreads();
    // transpose: T[h][row], 4-row groups XOR-swizzled to break bank conflicts
#pragma unroll
    for (int r = 0; r < 4; ++r)
#pragma unroll
        for (int k = 0; k < 4; ++k) {
            int h = hq * 4 + k;
            int row = rg * 4 + r;
            smem[h * 64 + (((row >> 2) ^ (h & 15)) << 2) + (row & 3)] = acc[r][k];
        }
    __syncthreads();

    const int h = t >> 2;    // 0..63
    const int rc = t & 3;    // 16-row chunk
    union { __bf16 bh[16]; uint4 u4[2]; } uh, ul;
#pragma unroll
    for (int q = 0; q < 4; ++q) {
        float4 v = *(const float4*)&smem[h * 64 + (((rc * 4 + q) ^ (h & 15)) << 2)];
        float vv[4] = {v.x, v.y, v.z, v.w};
#pragma unroll
        for (int e = 0; e < 4; ++e) {
            float val = vv[e];
            __bf16 hi = (__bf16)val;
            __bf16 lo = (__bf16)(val - (float)hi);
            uh.bh[q * 4 + e] = hi;
            ul.bh[q * 4 + e] = lo;
        }
    }
    size_t obase = (size_t)(b * HID + h) * NN + n0 + rc * 16;
    *(uint4*)&wht_hi[obase] = uh.u4[0];
    *(uint4*)&wht_hi[obase + 8] = uh.u4[1];
    *(uint4*)&wht_lo[obase] = ul.u4[0];
    *(uint4*)&wht_lo[obase + 8] = ul.u4[1];
}

// ---------------------------------------------------------------------------
// k2: f2max[b] = max_n f2[b][n]  (feeds the softmax shift bound)
// ---------------------------------------------------------------------------
__global__ __launch_bounds__(256) void k_f2max(
    const float* __restrict__ f2, float* __restrict__ f2mx)
{
    __shared__ float red[4];
    const int b = blockIdx.x, t = threadIdx.x;
    float m = -3.4e38f;
    for (int i = t; i < NN; i += 256) m = fmaxf(m, f2[b * NN + i]);
#pragma unroll
    for (int s = 1; s < 64; s <<= 1) m = fmaxf(m, __shfl_xor(m, s));
    if ((t & 63) == 0) red[t >> 6] = m;
    __syncthreads();
    if (t == 0) f2mx[b] = fmaxf(fmaxf(red[0], red[1]), fmaxf(red[2], red[3]));
}

// ---------------------------------------------------------------------------
// k3: fused adjacency-pack + masked-softmax + P@Wh (32x32x16 bf16 MFMA hi/lo).
// All global loads coalesced (ballot-pack adj, LDS-staged WhT, broadcast f2).
// JSPLIT=8 -> 1024 blocks = 4 blocks/CU = 16 waves/CU so phase-A HBM latency
// and stage barriers are hidden by wave rotation.
// ---------------------------------------------------------------------------
__global__ __launch_bounds__(256, 4) void k_attn(
    const int* __restrict__ adj, const __bf16* __restrict__ wht_hi,
    const __bf16* __restrict__ wht_lo, const float* __restrict__ f1,
    const float* __restrict__ f2, const float* __restrict__ f2mx,
    float* __restrict__ accp, float* __restrict__ zp)
{
    __shared__ __bf16 whi[64 * 128];   // [h][j-tile], 8-elem groups XOR-swizzled
    __shared__ __bf16 wlo[64 * 128];
    const int t = threadIdx.x;
    const int w = t >> 6, lane = t & 63;
    const int bx = blockIdx.x;
    const int js = bx & 7;
    const int it = (bx >> 3) & 15;
    const int b = bx >> 7;
    const int I0 = it * 128 + w * 32;
    const int half = lane >> 5;
    const int m32 = lane & 31;
    const int row = I0 + m32;
    const int jb0 = js * 256;

    const float f1v = f1[b * NN + row];
    float Mi = f1v + f2mx[b];
    Mi = Mi > 0.f ? Mi : 0.2f * Mi;            // lrelu monotone -> valid bound
    const float LOG2E = 1.4426950408889634f;
    const float negMiL = -Mi * LOG2E;
    const float* f2p = f2 + b * NN;

    // ---- Phase A: ballot-pack this wave's 32 adjacency rows (32 KB, coalesced)
    uint64_t mq[4];
#pragma unroll
    for (int k = 0; k < 4; ++k) mq[k] = 0;
    const int* adjbase = adj + ((size_t)b * NN + I0) * NN + jb0;
#pragma unroll 8
    for (int r = 0; r < 32; ++r) {
        const int* ar = adjbase + (size_t)r * NN;
        bool keep = (m32 == r);
#pragma unroll
        for (int k = 0; k < 4; ++k) {
            unsigned long long bal = __ballot(ar[k * 64 + lane] != 0);
            if (keep) mq[k] = bal;
        }
    }

    f32x16_t acc0, acc1;
#pragma unroll
    for (int i = 0; i < 16; ++i) { acc0[i] = 0.f; acc1[i] = 0.f; }
    float zacc = 0.f;

    for (int stg = 0; stg < 2; ++stg) {
        const int jt = jb0 + stg * 128;
        __syncthreads();
#pragma unroll
        for (int cc = 0; cc < 4; ++cc) {
            int c = t + cc * 256;
            int h = c >> 4, g = c & 15;
            int gp = g ^ (h & 15);
            size_t src = (size_t)(b * HID + h) * NN + jt + g * 8;
            *(uint4*)&whi[h * 128 + gp * 8] = *(const uint4*)&wht_hi[src];
            *(uint4*)&wlo[h * 128 + gp * 8] = *(const uint4*)&wht_lo[src];
        }
        __syncthreads();
#pragma unroll
        for (int s8 = 0; s8 < 8; ++s8) {
            const int jl = jt + s8 * 16 + half * 8;   // this lane's 8-j group
            const uint32_t bits8 =
                (uint32_t)(mq[s8 >> 2] >> (((s8 & 3) * 16) + half * 8)) & 0xffu;
            float4 fa = *(const float4*)&f2p[jl];
            float4 fb = *(const float4*)&f2p[jl + 4];
            float fv[8] = {fa.x, fa.y, fa.z, fa.w, fb.x, fb.y, fb.z, fb.w};
            bf16x8_t ahi, alo;
#pragma unroll
            for (int jj = 0; jj < 8; ++jj) {
                float t1 = f1v + fv[jj];
                t1 = fmaxf(t1, 0.2f * t1);
                float pv = (bits8 & (1u << jj))
                         ? __builtin_amdgcn_exp2f(fmaf(t1, LOG2E, negMiL))
                         : 0.f;
                zacc += pv;
                __bf16 hb = (__bf16)pv;
                ahi[jj] = hb;
                alo[jj] = (__bf16)(pv - (float)hb);
            }
            const int gb = 2 * s8 + half;
            const int gx = gb ^ (m32 & 15);
            bf16x8_t bh0 = *(const bf16x8_t*)&whi[m32 * 128 + (gx << 3)];
            bf16x8_t bl0 = *(const bf16x8_t*)&wlo[m32 * 128 + (gx << 3)];
            bf16x8_t bh1 = *(const bf16x8_t*)&whi[(m32 + 32) * 128 + (gx << 3)];
            bf16x8_t bl1 = *(const bf16x8_t*)&wlo[(m32 + 32) * 128 + (gx << 3)];
            acc0 = __builtin_amdgcn_mfma_f32_32x32x16_bf16(ahi, bh0, acc0, 0, 0, 0);
            acc0 = __builtin_amdgcn_mfma_f32_32x32x16_bf16(ahi, bl0, acc0, 0, 0, 0);
            acc0 = __builtin_amdgcn_mfma_f32_32x32x16_bf16(alo, bh0, acc0, 0, 0, 0);
            acc1 = __builtin_amdgcn_mfma_f32_32x32x16_bf16(ahi, bh1, acc1, 0, 0, 0);
            acc1 = __builtin_amdgcn_mfma_f32_32x32x16_bf16(ahi, bl1, acc1, 0, 0, 0);
            acc1 = __builtin_amdgcn_mfma_f32_32x32x16_bf16(alo, bh1, acc1, 0, 0, 0);
        }
        // shift mask queue so next stage uses mq[0], mq[1] (const indices)
#pragma unroll
        for (int k = 0; k < 2; ++k) mq[k] = mq[k + 2];
    }

    float zrow = zacc + __shfl_xor(zacc, 32);
    if (lane < 32) zp[(size_t)(js * NB + b) * NN + row] = zrow;
    float* ap = accp + (size_t)(js * NB + b) * NN * HID;
#pragma unroll
    for (int r = 0; r < 16; ++r) {
        int rr = (r & 3) + 8 * (r >> 2) + 4 * half;   // verified C-layout (m74/m101)
        ap[(size_t)(I0 + rr) * HID + m32] = acc0[r];
        ap[(size_t)(I0 + rr) * HID + m32 + 32] = acc1[r];
    }
}

// ---------------------------------------------------------------------------
// k4: out = (sum_js acc_js) / (sum_js Z_js)
// ---------------------------------------------------------------------------
__global__ __launch_bounds__(256) void k_combine(
    const float* __restrict__ accp, const float* __restrict__ zp,
    float* __restrict__ out)
{
    int gid = blockIdx.x * 256 + threadIdx.x;   // 0..262143 (float4 granules)
    int h4 = gid & 15;
    int rowg = gid >> 4;                        // b*N + n
    float z = 0.f;
    float sx = 0.f, sy = 0.f, sz = 0.f, sw = 0.f;
#pragma unroll
    for (int js = 0; js < JSPLIT; ++js) {
        size_t base = (size_t)js * NB * NN;
        z += zp[base + rowg];
        float4 v = ((const float4*)accp)[(base + rowg) * 16 + h4];
        sx += v.x; sy += v.y; sz += v.z; sw += v.w;
    }
    float zi = 1.f / z;
    float4 o = {sx * zi, sy * zi, sz * zi, sw * zi};
    ((float4*)out)[gid] = o;
}

extern "C" void kernel_launch(void* const* d_in, const int* in_sizes, int n_in,
                              void* d_out, int out_size, void* d_ws, size_t ws_size,
                              hipStream_t stream)
{
    const float* x = (const float*)d_in[0];
    const int* adj = (const int*)d_in[1];
    const float* W = (const float*)d_in[2];
    const float* a = (const float*)d_in[3];
    float* out = (float*)d_out;
    char* ws = (char*)d_ws;

    __bf16* wht_hi = (__bf16*)(ws);                          // 2 MB
    __bf16* wht_lo = (__bf16*)(ws + (2u << 20));             // 2 MB
    float* f1   = (float*)(ws + (4u << 20));                 // 64 KB
    float* f2   = (float*)(ws + (4u << 20) + (64u << 10));   // 64 KB
    float* f2mx = (float*)(ws + (4u << 20) + (128u << 10));  // 32 B
    float* accp = (float*)(ws + (5u << 20));                 // 32 MB (8 splits)
    float* zp   = (float*)(ws + (37u << 20));                // 512 KB

    hipLaunchKernelGGL(k_wh, dim3(256), dim3(256), 0, stream, x, W, a, wht_hi, wht_lo, f1, f2);
    hipLaunchKernelGGL(k_f2max, dim3(NB), dim3(256), 0, stream, f2, f2mx);
    hipLaunchKernelGGL(k_attn, dim3(1024), dim3(256), 0, stream, adj, wht_hi, wht_lo, f1, f2, f2mx, accp, zp);
    hipLaunchKernelGGL(k_combine, dim3(1024), dim3(256), 0, stream, accp, zp, out);
}